// Round 1
// baseline (205.341 us; speedup 1.0000x reference)
//
#include <hip/hip_runtime.h>
#include <hip/hip_bf16.h>
#include <hip/hip_cooperative_groups.h>

namespace cg = cooperative_groups;

#define DD 256
#define NN 512

typedef __attribute__((ext_vector_type(8))) short short8;
typedef __attribute__((ext_vector_type(4))) float floatx4;

// ---- f32 -> bf16 round-to-nearest-even ----
__device__ __forceinline__ unsigned short f2bf(float f) {
  unsigned u = __float_as_uint(f);
  u += 0x7FFFu + ((u >> 16) & 1u);
  return (unsigned short)(u >> 16);
}
__device__ __forceinline__ unsigned pack2(float a, float b) {
  return (unsigned)f2bf(a) | ((unsigned)f2bf(b) << 16);
}

// ---- MFMA fragment from global bf16 rows (k contiguous): one 16B load ----
__device__ __forceinline__ short8 ldfrag(const unsigned short* __restrict__ base,
                                         int row, int ld, int k, int lane) {
  return *(const short8*)(base + (row + (lane & 15)) * ld + k + ((lane >> 4) << 3));
}

// ---- MFMA fragment from global f32 rows (k contiguous): 2 float4 + pack ----
__device__ __forceinline__ short8 ldfrag_f32(const float* __restrict__ base,
                                             int row, int ld, int k, int lane) {
  const float* p = base + (row + (lane & 15)) * ld + k + ((lane >> 4) << 3);
  const float4 v0 = *(const float4*)p;
  const float4 v1 = *(const float4*)(p + 4);
  short8 r;
  r[0] = (short)f2bf(v0.x); r[1] = (short)f2bf(v0.y);
  r[2] = (short)f2bf(v0.z); r[3] = (short)f2bf(v0.w);
  r[4] = (short)f2bf(v1.x); r[5] = (short)f2bf(v1.y);
  r[6] = (short)f2bf(v1.z); r[7] = (short)f2bf(v1.w);
  return r;
}

// ---- MFMA fragment, TRANSPOSED, direct from global f32 [k][n] storage -----
__device__ __forceinline__ short8 ldfragT_g(const float* __restrict__ base,
                                            int n0, int ld, int k, int lane) {
  const int n = n0 + (lane & 15);
  const int kk = k + ((lane >> 4) << 3);
  short8 r;
#pragma unroll
  for (int j = 0; j < 8; ++j) r[j] = (short)f2bf(base[(kk + j) * ld + n]);
  return r;
}

template <int NF>
__device__ __forceinline__ void acc_zero(floatx4 acc[NF]) {
#pragma unroll
  for (int i = 0; i < NF; ++i) {
    acc[i][0] = 0.f; acc[i][1] = 0.f; acc[i][2] = 0.f; acc[i][3] = 0.f;
  }
}

// Split-K combine across 4 waves via LDS; wave 0 ends with the full sum.
template <int NF>
__device__ __forceinline__ void ksplit_combine(floatx4 acc[NF], float* red,
                                               int wave, int lane) {
  const int W = 16 * NF;
  const int col = lane & 15;
  const int q = lane >> 4;
  if (wave > 0) {
    float* base = red + (wave - 1) * 16 * W;
#pragma unroll
    for (int nf = 0; nf < NF; ++nf)
#pragma unroll
      for (int r = 0; r < 4; ++r)
        base[(q * 4 + r) * W + nf * 16 + col] = acc[nf][r];
  }
  __syncthreads();
  if (wave == 0) {
#pragma unroll
    for (int nf = 0; nf < NF; ++nf)
#pragma unroll
      for (int r = 0; r < 4; ++r) {
        const int idx = (q * 4 + r) * W + nf * 16 + col;
        acc[nf][r] += red[idx] + red[16 * W + idx] + red[32 * W + idx];
      }
  }
}

// Epilogue for C-layout (col = lane&15, row = (lane>>4)*4 + r).
template <int NF, bool COLBIAS, bool ROWBIAS, bool RELU, bool OUTBF>
__device__ __forceinline__ void gemm_epi(floatx4 acc[NF],
    const float* __restrict__ bias, void* __restrict__ C, int ldc,
    int m0, int n0, int lane) {
  const int col = lane & 15;
  const int q = lane >> 4;
#pragma unroll
  for (int nf = 0; nf < NF; ++nf) {
    const int n = n0 + nf * 16 + col;
    const float cb = COLBIAS ? bias[n] : 0.0f;
#pragma unroll
    for (int r = 0; r < 4; ++r) {
      const int m = m0 + q * 4 + r;
      float v = acc[nf][r] + cb + (ROWBIAS ? bias[m] : 0.0f);
      if (RELU) v = fmaxf(v, 0.0f);
      if (OUTBF) ((unsigned short*)C)[m * ldc + n] = f2bf(v);
      else       ((float*)C)[m * ldc + n] = v;
    }
  }
}

// ---------------------------------------------------------------------------
// Single cooperative kernel: 256 blocks x 256 threads, 1 block/CU.
// Phase 1: aqak (+ y init + xT cvt)   [former aqak_kernel, 768 -> 256 blocks]
// Phase 2: scores                     [former scores_kernel]
// Phase 3: softmax + P@src^T          [former msgT_kernel]
// Phase 4: h2 + y accumulation        [former h2y_kernel]
// grid.sync() between phases replaces 3 kernel-launch boundaries.
// ---------------------------------------------------------------------------
union SMem {
  float red[1536];                       // phase 1 split-K combine
  struct {                               // phase 2 (91136 B — the max)
    float aqs[256][36];
    float aks[256][36];
    float part[4][32][32];
    float w2s[DD];
  } s2;
  struct {                               // phase 3
    unsigned short Ap[16][520];
    float red[1536];
    float smax[16][16];
    float ssum[16][16];
    float rst[16][2];
  } s3;
  unsigned short h2L[16][72];            // phase 4
};

__global__ __launch_bounds__(256) void fused_kernel(
    const float* __restrict__ x, const float* __restrict__ src,
    const float* __restrict__ w1, const float* __restrict__ b1,
    const float* __restrict__ w2, const float* __restrict__ b2,
    const float* __restrict__ wa, const float* __restrict__ ba,
    const float* __restrict__ wb, const float* __restrict__ bb,
    float* __restrict__ y, float* __restrict__ sc,
    float* __restrict__ aq, float* __restrict__ ak,
    unsigned short* __restrict__ msgTb, unsigned short* __restrict__ xT) {
  __shared__ __align__(16) SMem sm;
  cg::grid_group grid = cg::this_grid();

  const int tid = threadIdx.x;
  const int b = blockIdx.x;
  const int lane = tid & 63;
  const int wave = tid >> 6;

  // ================= phase 1: y init + xT cvt + aq/ak GEMM =================
  {
    // former z==2 unit: block b handles row b of y and tokens 2b, 2b+1 of xT
    const float bv = bb[b];
    float2 v2; v2.x = bv; v2.y = bv;
    *(float2*)&y[b * NN + tid * 2] = v2;
    const int n0t = b * 2 + (tid >> 7);
    const int d2 = (tid & 127) * 2;
    const float f0 = x[d2 * NN + n0t];
    const float f1 = x[(d2 + 1) * NN + n0t];
    *(unsigned*)&xT[n0t * DD + d2] = pack2(f0, f1);
  }
  {
    const int m0 = (b >> 4) * 16;   // d
    const int n0 = (b & 15) * 32;   // token
#pragma unroll
    for (int z = 0; z < 2; ++z) {
      const float* in = z ? src : x;
      floatx4 acc[2]; acc_zero<2>(acc);
#pragma unroll
      for (int kc = 0; kc < 2; ++kc) {
        const int kl = wave * 64 + kc * 32;
        short8 a = ldfrag_f32(w1, m0, NN, z * 256 + kl, lane);
#pragma unroll
        for (int nf = 0; nf < 2; ++nf) {
          short8 bf = ldfragT_g(in, n0 + nf * 16, NN, kl, lane);
          acc[nf] = __builtin_amdgcn_mfma_f32_16x16x32_bf16(a, bf, acc[nf], 0, 0, 0);
        }
      }
      if (z) __syncthreads();   // wave0's z=0 reads of red must finish first
      ksplit_combine<2>(acc, sm.red, wave, lane);
      if (wave == 0) {
        if (z == 0) gemm_epi<2, false, true, false, false>(acc, b1, aq, NN, m0, n0, lane);
        else        gemm_epi<2, false, false, false, false>(acc, nullptr, ak, NN, m0, n0, lane);
      }
    }
  }
  grid.sync();

  // ================= phase 2: scores ======================================
  {
    const int n0 = (b & 15) * 32;
    const int m0 = (b >> 4) * 32;

    sm.s2.w2s[tid] = w2[tid];

    // stage aq/ak tiles (f32, coalesced 128B groups)
#pragma unroll
    for (int i = 0; i < 8; ++i) {
      const int idx = i * 256 + tid;
      const int row = idx >> 3;
      const int c4 = (idx & 7) * 4;
      *(float4*)&sm.s2.aqs[row][c4] = *(const float4*)&aq[row * NN + n0 + c4];
      *(float4*)&sm.s2.aks[row][c4] = *(const float4*)&ak[row * NN + m0 + c4];
    }
    __syncthreads();

    // outer-product phase: wave covers 64 d; lane = (nq 0..7, mq 0..7)
    {
      const int nq = lane & 7;
      const int mq = lane >> 3;
      float s[4][4];
#pragma unroll
      for (int i = 0; i < 4; ++i)
#pragma unroll
        for (int j = 0; j < 4; ++j) s[i][j] = 0.f;

      const int dbeg = wave * 64;
      for (int dd = dbeg; dd < dbeg + 64; ++dd) {
        const float4 a4 = *(const float4*)&sm.s2.aqs[dd][nq * 4];
        const float4 k4 = *(const float4*)&sm.s2.aks[dd][mq * 4];
        const float w = sm.s2.w2s[dd];
        const float a[4] = {a4.x, a4.y, a4.z, a4.w};
        const float k[4] = {k4.x, k4.y, k4.z, k4.w};
#pragma unroll
        for (int i = 0; i < 4; ++i)
#pragma unroll
          for (int j = 0; j < 4; ++j)
            s[i][j] += w * fmaxf(a[i] + k[j], 0.f);
      }
#pragma unroll
      for (int i = 0; i < 4; ++i) {
        float4 o; o.x = s[i][0]; o.y = s[i][1]; o.z = s[i][2]; o.w = s[i][3];
        *(float4*)&sm.s2.part[wave][nq * 4 + i][mq * 4] = o;
      }
    }
    __syncthreads();

    // combine 4 wave-partials + b2, write sc
    {
      const int n = tid >> 3;
      const int mg = (tid & 7) * 4;
      const float4 p0 = *(const float4*)&sm.s2.part[0][n][mg];
      const float4 p1 = *(const float4*)&sm.s2.part[1][n][mg];
      const float4 p2 = *(const float4*)&sm.s2.part[2][n][mg];
      const float4 p3 = *(const float4*)&sm.s2.part[3][n][mg];
      const float bv = b2[0];
      float4 o;
      o.x = p0.x + p1.x + p2.x + p3.x + bv;
      o.y = p0.y + p1.y + p2.y + p3.y + bv;
      o.z = p0.z + p1.z + p2.z + p3.z + bv;
      o.w = p0.w + p1.w + p2.w + p3.w + bv;
      *(float4*)&sc[(n0 + n) * NN + m0 + mg] = o;
    }
  }
  grid.sync();

  // ================= phase 3: softmax + P @ src^T =========================
  {
    const int n0 = (b >> 3) * 16;
    const int d0 = (b & 7) * 32;

    const int r = tid >> 4;
    const int c = tid & 15;
    float4 v[8];
    const float* rp = sc + (n0 + r) * NN + c * 4;
#pragma unroll
    for (int i = 0; i < 8; ++i) v[i] = *(const float4*)(rp + i * 64);

    float mx = -3.0e38f;
#pragma unroll
    for (int i = 0; i < 8; ++i)
      mx = fmaxf(mx, fmaxf(fmaxf(v[i].x, v[i].y), fmaxf(v[i].z, v[i].w)));
    sm.s3.smax[r][c] = mx;
    __syncthreads();
    if (c == 0) {
      float m2 = sm.s3.smax[r][0];
#pragma unroll
      for (int i = 1; i < 16; ++i) m2 = fmaxf(m2, sm.s3.smax[r][i]);
      sm.s3.rst[r][0] = m2;
    }
    __syncthreads();
    mx = sm.s3.rst[r][0];

    float sum = 0.f;
#pragma unroll
    for (int i = 0; i < 8; ++i) {
      v[i].x = __expf(v[i].x - mx); v[i].y = __expf(v[i].y - mx);
      v[i].z = __expf(v[i].z - mx); v[i].w = __expf(v[i].w - mx);
      sum += v[i].x + v[i].y + v[i].z + v[i].w;
    }
    sm.s3.ssum[r][c] = sum;
    __syncthreads();
    if (c == 0) {
      float s2 = sm.s3.ssum[r][0];
#pragma unroll
      for (int i = 1; i < 16; ++i) s2 += sm.s3.ssum[r][i];
      sm.s3.rst[r][1] = s2;
    }
    __syncthreads();
    const float inv = 1.0f / sm.s3.rst[r][1];
#pragma unroll
    for (int i = 0; i < 8; ++i) {
      *(unsigned*)&sm.s3.Ap[r][c * 4 + i * 64]     = pack2(v[i].x * inv, v[i].y * inv);
      *(unsigned*)&sm.s3.Ap[r][c * 4 + i * 64 + 2] = pack2(v[i].z * inv, v[i].w * inv);
    }
    __syncthreads();

    floatx4 acc[2]; acc_zero<2>(acc);
    const int k0w = wave * 128;
    const int arow = lane & 15;
    const int koff = (lane >> 4) << 3;
#pragma unroll
    for (int k = 0; k < 128; k += 32) {
      short8 a = *(const short8*)&sm.s3.Ap[arow][k0w + k + koff];
#pragma unroll
      for (int nf = 0; nf < 2; ++nf) {
        short8 bf = ldfrag_f32(src, d0 + nf * 16, NN, k0w + k, lane);
        acc[nf] = __builtin_amdgcn_mfma_f32_16x16x32_bf16(a, bf, acc[nf], 0, 0, 0);
      }
    }
    ksplit_combine<2>(acc, sm.s3.red, wave, lane);
    if (wave == 0)
      gemm_epi<2, false, false, false, true>(acc, nullptr, msgTb, DD, n0, d0, lane);
  }
  grid.sync();

  // ================= phase 4: h2 + y accumulation =========================
  {
    const int o0 = (b & 7) * 64;
    const int n0g = (b >> 3) * 16;

    // phase 4a: h2L[n][o_local], wave owns 16 o
    {
      floatx4 acc;
      acc[0] = 0.f; acc[1] = 0.f; acc[2] = 0.f; acc[3] = 0.f;
      const int ow = o0 + wave * 16;
#pragma unroll
      for (int kc = 0; kc < 16; ++kc) {
        const int c0 = kc * 32;
        short8 a = (c0 < 256) ? ldfrag(xT, n0g, DD, c0, lane)
                              : ldfrag(msgTb, n0g, DD, c0 - 256, lane);
        short8 bf = ldfrag_f32(wa, ow, NN, c0, lane);
        acc = __builtin_amdgcn_mfma_f32_16x16x32_bf16(a, bf, acc, 0, 0, 0);
      }
      const int col = lane & 15, q = lane >> 4;
      const float cb = ba[o0 + wave * 16 + col];
#pragma unroll
      for (int r = 0; r < 4; ++r)
        sm.h2L[q * 4 + r][wave * 16 + col] = f2bf(fmaxf(acc[r] + cb, 0.f));
    }
    __syncthreads();

    // phase 4b: y[o2][n] += wb[o2][o0:o0+64] @ h2L^T
    {
      const int brow = lane & 15;
      const int koff = (lane >> 4) << 3;
      const int col = lane & 15, q = lane >> 4;
#pragma unroll
      for (int t = 0; t < 4; ++t) {
        const int o2t = wave * 64 + t * 16;
        floatx4 acc;
        acc[0] = 0.f; acc[1] = 0.f; acc[2] = 0.f; acc[3] = 0.f;
#pragma unroll
        for (int kc = 0; kc < 2; ++kc) {
          short8 a = ldfrag_f32(wb, o2t, NN, o0 + kc * 32, lane);
          short8 bf = *(const short8*)&sm.h2L[brow][kc * 32 + koff];
          acc = __builtin_amdgcn_mfma_f32_16x16x32_bf16(a, bf, acc, 0, 0, 0);
        }
#pragma unroll
        for (int r = 0; r < 4; ++r)
          atomicAdd(&y[(o2t + q * 4 + r) * NN + n0g + col], acc[r]);
      }
    }
  }
}

// ---------------------------------------------------------------------------
extern "C" void kernel_launch(void* const* d_in, const int* in_sizes, int n_in,
                              void* d_out, int out_size, void* d_ws, size_t ws_size,
                              hipStream_t stream) {
  (void)in_sizes; (void)n_in; (void)out_size; (void)ws_size;

  const float* x   = (const float*)d_in[0];
  const float* src = (const float*)d_in[1];
  const float* w1  = (const float*)d_in[2];
  const float* b1  = (const float*)d_in[3];
  const float* w2  = (const float*)d_in[4];
  const float* b2  = (const float*)d_in[5];
  const float* wa  = (const float*)d_in[6];
  const float* ba  = (const float*)d_in[7];
  const float* wb  = (const float*)d_in[8];
  const float* bb  = (const float*)d_in[9];

  float* y_out  = (float*)d_out;            // (256,512)
  float* sc_out = (float*)d_out + 131072;   // (512,512)

  char* ws = (char*)d_ws;
  float*          aq    = (float*)(ws);                          // 512KB
  float*          ak    = (float*)(ws + (512 << 10));            // 512KB
  unsigned short* msgTb = (unsigned short*)(ws + (1024 << 10));  // 256KB
  unsigned short* xT    = (unsigned short*)(ws + (1280 << 10));  // 256KB

  void* args[16];
  args[0]  = (void*)&x;     args[1]  = (void*)&src;
  args[2]  = (void*)&w1;    args[3]  = (void*)&b1;
  args[4]  = (void*)&w2;    args[5]  = (void*)&b2;
  args[6]  = (void*)&wa;    args[7]  = (void*)&ba;
  args[8]  = (void*)&wb;    args[9]  = (void*)&bb;
  args[10] = (void*)&y_out; args[11] = (void*)&sc_out;
  args[12] = (void*)&aq;    args[13] = (void*)&ak;
  args[14] = (void*)&msgTb; args[15] = (void*)&xT;

  hipLaunchCooperativeKernel(fused_kernel, dim3(256), dim3(256), args, 0, stream);
}

// Round 2
// 101.726 us; speedup vs baseline: 2.0186x; 2.0186x over previous
//
#include <hip/hip_runtime.h>
#include <hip/hip_bf16.h>

#define DD 256
#define NN 512

typedef __attribute__((ext_vector_type(8))) short short8;
typedef __attribute__((ext_vector_type(4))) float floatx4;

// ---- f32 -> bf16 round-to-nearest-even ----
__device__ __forceinline__ unsigned short f2bf(float f) {
  unsigned u = __float_as_uint(f);
  u += 0x7FFFu + ((u >> 16) & 1u);
  return (unsigned short)(u >> 16);
}
__device__ __forceinline__ unsigned pack2(float a, float b) {
  return (unsigned)f2bf(a) | ((unsigned)f2bf(b) << 16);
}

// ---- MFMA fragment from global bf16 rows (k contiguous): one 16B load ----
__device__ __forceinline__ short8 ldfrag(const unsigned short* __restrict__ base,
                                         int row, int ld, int k, int lane) {
  return *(const short8*)(base + (row + (lane & 15)) * ld + k + ((lane >> 4) << 3));
}

// ---- MFMA fragment from global f32 rows (k contiguous): 2 float4 + pack ----
__device__ __forceinline__ short8 ldfrag_f32(const float* __restrict__ base,
                                             int row, int ld, int k, int lane) {
  const float* p = base + (row + (lane & 15)) * ld + k + ((lane >> 4) << 3);
  const float4 v0 = *(const float4*)p;
  const float4 v1 = *(const float4*)(p + 4);
  short8 r;
  r[0] = (short)f2bf(v0.x); r[1] = (short)f2bf(v0.y);
  r[2] = (short)f2bf(v0.z); r[3] = (short)f2bf(v0.w);
  r[4] = (short)f2bf(v1.x); r[5] = (short)f2bf(v1.y);
  r[6] = (short)f2bf(v1.z); r[7] = (short)f2bf(v1.w);
  return r;
}

template <int NF>
__device__ __forceinline__ void acc_zero(floatx4 acc[NF]) {
#pragma unroll
  for (int i = 0; i < NF; ++i) {
    acc[i][0] = 0.f; acc[i][1] = 0.f; acc[i][2] = 0.f; acc[i][3] = 0.f;
  }
}

// Split-K combine across 4 waves via LDS; wave 0 ends with the full sum.
template <int NF>
__device__ __forceinline__ void ksplit_combine(floatx4 acc[NF], float* red,
                                               int wave, int lane) {
  const int W = 16 * NF;
  const int col = lane & 15;
  const int q = lane >> 4;
  if (wave > 0) {
    float* base = red + (wave - 1) * 16 * W;
#pragma unroll
    for (int nf = 0; nf < NF; ++nf)
#pragma unroll
      for (int r = 0; r < 4; ++r)
        base[(q * 4 + r) * W + nf * 16 + col] = acc[nf][r];
  }
  __syncthreads();
  if (wave == 0) {
#pragma unroll
    for (int nf = 0; nf < NF; ++nf)
#pragma unroll
      for (int r = 0; r < 4; ++r) {
        const int idx = (q * 4 + r) * W + nf * 16 + col;
        acc[nf][r] += red[idx] + red[16 * W + idx] + red[32 * W + idx];
      }
  }
}

// Epilogue for C-layout (col = lane&15, row = (lane>>4)*4 + r).
template <int NF, bool COLBIAS, bool ROWBIAS, bool RELU, bool OUTBF>
__device__ __forceinline__ void gemm_epi(floatx4 acc[NF],
    const float* __restrict__ bias, void* __restrict__ C, int ldc,
    int m0, int n0, int lane) {
  const int col = lane & 15;
  const int q = lane >> 4;
#pragma unroll
  for (int nf = 0; nf < NF; ++nf) {
    const int n = n0 + nf * 16 + col;
    const float cb = COLBIAS ? bias[n] : 0.0f;
#pragma unroll
    for (int r = 0; r < 4; ++r) {
      const int m = m0 + q * 4 + r;
      float v = acc[nf][r] + cb + (ROWBIAS ? bias[m] : 0.0f);
      if (RELU) v = fmaxf(v, 0.0f);
      if (OUTBF) ((unsigned short*)C)[m * ldc + n] = f2bf(v);
      else       ((float*)C)[m * ldc + n] = v;
    }
  }
}

// ---------------------------------------------------------------------------
// aqak: aq[d][n] = w1[:, :256] @ x + b1 ; ak[d][n] = w1[:, 256:] @ src (f32).
// grid (16, 16, 3); z==2 blocks: y[o][:] = bb[o] AND emit xT bf16 [n][d].
// B-operand (x/src tile, transposed) staged via LDS with coalesced float4
// loads instead of 8x stride-2KB scalar global loads per fragment.
// ---------------------------------------------------------------------------
__global__ __launch_bounds__(256) void aqak_kernel(
    const float* __restrict__ x, const float* __restrict__ src,
    const float* __restrict__ w1, const float* __restrict__ b1,
    const float* __restrict__ bb,
    float* __restrict__ aq, float* __restrict__ ak, float* __restrict__ y,
    unsigned short* __restrict__ xT) {
  __shared__ float red[1536];
  __shared__ __align__(16) float bt[256][33];   // [d][n], +1 pad breaks conflicts

  const int tid = threadIdx.x;
  const int z = blockIdx.z;

  if (z == 2) {
    const int c = blockIdx.y * 16 + blockIdx.x;   // 0..255
    const float bv = bb[c];
    float2 v; v.x = bv; v.y = bv;
    *(float2*)&y[c * NN + tid * 2] = v;
    const int n0t = c * 2 + (tid >> 7);
    const int d2 = (tid & 127) * 2;
    const float f0 = x[d2 * NN + n0t];
    const float f1 = x[(d2 + 1) * NN + n0t];
    *(unsigned*)&xT[n0t * DD + d2] = pack2(f0, f1);
    return;
  }

  const int lane = tid & 63;
  const int wave = tid >> 6;
  const int m0 = blockIdx.y * 16;   // d
  const int n0 = blockIdx.x * 32;   // token
  const float* in = z ? src : x;

  // ---- stage [256 d][32 n] f32 tile, coalesced 128B groups ----
#pragma unroll
  for (int i = 0; i < 8; ++i) {
    const int idx = i * 256 + tid;
    const int row = idx >> 3;
    const int c4 = (idx & 7) * 4;
    *(float4*)&bt[row][c4] = *(const float4*)&in[row * NN + n0 + c4];
  }
  __syncthreads();

  floatx4 acc[2]; acc_zero<2>(acc);
#pragma unroll
  for (int kc = 0; kc < 2; ++kc) {
    const int kl = wave * 64 + kc * 32;
    short8 a = ldfrag_f32(w1, m0, NN, z * 256 + kl, lane);
#pragma unroll
    for (int nf = 0; nf < 2; ++nf) {
      const int n = nf * 16 + (lane & 15);
      const int kk = kl + ((lane >> 4) << 3);
      short8 b;
#pragma unroll
      for (int j = 0; j < 8; ++j) b[j] = (short)f2bf(bt[kk + j][n]);
      acc[nf] = __builtin_amdgcn_mfma_f32_16x16x32_bf16(a, b, acc[nf], 0, 0, 0);
    }
  }
  ksplit_combine<2>(acc, red, wave, lane);
  if (wave == 0) {
    if (z == 0) gemm_epi<2, false, true, false, false>(acc, b1, aq, NN, m0, n0, lane);
    else        gemm_epi<2, false, false, false, false>(acc, nullptr, ak, NN, m0, n0, lane);
  }
}

// ---------------------------------------------------------------------------
// scores: sc[n][m] = b2 + sum_d w2[d] relu(aq[d][n] + ak[d][m])
// grid (16,16) x 512 threads. d split across 8 waves (2 waves/SIMD for
// stall interleave); lane does 4n x 4m outer-product from f32 LDS.
// ---------------------------------------------------------------------------
__global__ __launch_bounds__(512) void scores_kernel(
    const float* __restrict__ aq, const float* __restrict__ ak,
    const float* __restrict__ w2, const float* __restrict__ b2,
    float* __restrict__ sc) {
  __shared__ __align__(16) float aqs[256][36];   // [d][n], 144B rows
  __shared__ __align__(16) float aks[256][36];
  __shared__ __align__(16) float part[8][32][32];
  __shared__ float w2s[DD];

  const int tid = threadIdx.x;
  const int lane = tid & 63;
  const int wave = tid >> 6;
  const int n0 = blockIdx.x * 32;
  const int m0 = blockIdx.y * 32;

  if (tid < DD) w2s[tid] = w2[tid];

  // ---- stage aq/ak tiles (f32, coalesced 128B groups) ----
#pragma unroll
  for (int i = 0; i < 4; ++i) {
    const int idx = i * 512 + tid;
    const int row = idx >> 3;
    const int c4 = (idx & 7) * 4;
    *(float4*)&aqs[row][c4] = *(const float4*)&aq[row * NN + n0 + c4];
    *(float4*)&aks[row][c4] = *(const float4*)&ak[row * NN + m0 + c4];
  }
  __syncthreads();

  // ---- outer-product phase: wave covers 32 d; lane = (nq 0..7, mq 0..7) ----
  {
    const int nq = lane & 7;
    const int mq = lane >> 3;
    float s[4][4];
#pragma unroll
    for (int i = 0; i < 4; ++i)
#pragma unroll
      for (int j = 0; j < 4; ++j) s[i][j] = 0.f;

    const int dbeg = wave * 32;
    for (int dd = dbeg; dd < dbeg + 32; ++dd) {
      const float4 a4 = *(const float4*)&aqs[dd][nq * 4];
      const float4 k4 = *(const float4*)&aks[dd][mq * 4];
      const float w = w2s[dd];
      const float a[4] = {a4.x, a4.y, a4.z, a4.w};
      const float k[4] = {k4.x, k4.y, k4.z, k4.w};
#pragma unroll
      for (int i = 0; i < 4; ++i)
#pragma unroll
        for (int j = 0; j < 4; ++j)
          s[i][j] += w * fmaxf(a[i] + k[j], 0.f);
    }
#pragma unroll
    for (int i = 0; i < 4; ++i) {
      float4 o; o.x = s[i][0]; o.y = s[i][1]; o.z = s[i][2]; o.w = s[i][3];
      *(float4*)&part[wave][nq * 4 + i][mq * 4] = o;
    }
  }
  __syncthreads();

  // ---- combine 8 wave-partials + b2, write sc ----
  if (tid < 256) {
    const int n = tid >> 3;
    const int mg = (tid & 7) * 4;
    const float bv = b2[0];
    float4 o; o.x = bv; o.y = bv; o.z = bv; o.w = bv;
#pragma unroll
    for (int wv = 0; wv < 8; ++wv) {
      const float4 p = *(const float4*)&part[wv][n][mg];
      o.x += p.x; o.y += p.y; o.z += p.z; o.w += p.w;
    }
    *(float4*)&sc[(n0 + n) * NN + m0 + mg] = o;
  }
}

// ---------------------------------------------------------------------------
// msgT: softmax(sc rows) fused with P @ src^T (bf16 out); src read f32.
// grid (8 d-tiles of 32, 32 n-tiles) = 256 blocks; split-K/4 over m.
// ---------------------------------------------------------------------------
__global__ __launch_bounds__(256) void msgT_kernel(
    const float* __restrict__ sc, const float* __restrict__ srcf,
    unsigned short* __restrict__ msgTb) {
  __shared__ unsigned short Ap[16][520];
  __shared__ float red[1536];
  __shared__ float smax[16][16];
  __shared__ float ssum[16][16];
  __shared__ float rst[16][2];

  const int tid = threadIdx.x;
  const int lane = tid & 63;
  const int wave = tid >> 6;
  const int n0 = blockIdx.y * 16;
  const int d0 = blockIdx.x * 32;

  const int r = tid >> 4;
  const int c = tid & 15;
  float4 v[8];
  const float* rp = sc + (n0 + r) * NN + c * 4;
#pragma unroll
  for (int i = 0; i < 8; ++i) v[i] = *(const float4*)(rp + i * 64);

  float mx = -3.0e38f;
#pragma unroll
  for (int i = 0; i < 8; ++i)
    mx = fmaxf(mx, fmaxf(fmaxf(v[i].x, v[i].y), fmaxf(v[i].z, v[i].w)));
  smax[r][c] = mx;
  __syncthreads();
  if (c == 0) {
    float m2 = smax[r][0];
#pragma unroll
    for (int i = 1; i < 16; ++i) m2 = fmaxf(m2, smax[r][i]);
    rst[r][0] = m2;
  }
  __syncthreads();
  mx = rst[r][0];

  float sum = 0.f;
#pragma unroll
  for (int i = 0; i < 8; ++i) {
    v[i].x = __expf(v[i].x - mx); v[i].y = __expf(v[i].y - mx);
    v[i].z = __expf(v[i].z - mx); v[i].w = __expf(v[i].w - mx);
    sum += v[i].x + v[i].y + v[i].z + v[i].w;
  }
  ssum[r][c] = sum;
  __syncthreads();
  if (c == 0) {
    float s2 = ssum[r][0];
#pragma unroll
    for (int i = 1; i < 16; ++i) s2 += ssum[r][i];
    rst[r][1] = s2;
  }
  __syncthreads();
  const float inv = 1.0f / rst[r][1];
#pragma unroll
  for (int i = 0; i < 8; ++i) {
    *(unsigned*)&Ap[r][c * 4 + i * 64]     = pack2(v[i].x * inv, v[i].y * inv);
    *(unsigned*)&Ap[r][c * 4 + i * 64 + 2] = pack2(v[i].z * inv, v[i].w * inv);
  }
  __syncthreads();

  floatx4 acc[2]; acc_zero<2>(acc);
  const int k0w = wave * 128;
  const int arow = lane & 15;
  const int koff = (lane >> 4) << 3;
#pragma unroll
  for (int k = 0; k < 128; k += 32) {
    short8 a = *(const short8*)&Ap[arow][k0w + k + koff];
#pragma unroll
    for (int nf = 0; nf < 2; ++nf) {
      short8 b = ldfrag_f32(srcf, d0 + nf * 16, NN, k0w + k, lane);
      acc[nf] = __builtin_amdgcn_mfma_f32_16x16x32_bf16(a, b, acc[nf], 0, 0, 0);
    }
  }
  ksplit_combine<2>(acc, red, wave, lane);
  if (wave == 0)
    gemm_epi<2, false, false, false, true>(acc, nullptr, msgTb, DD, n0, d0, lane);
}

// ---------------------------------------------------------------------------
// h2y: h2 o-slice = relu([x|msg] @ wa^T + ba) in LDS (bf16), then
//      y[o2][n] += wb[o2][o-slice] @ h2^T via f32 atomicAdd (y pre-set to bb).
// grid (8 o-slices of 64, 32 n-tiles of 16). x read via precomputed xT bf16.
// ---------------------------------------------------------------------------
__global__ __launch_bounds__(256) void h2y_kernel(
    const unsigned short* __restrict__ xT, const unsigned short* __restrict__ msgTb,
    const float* __restrict__ waf, const float* __restrict__ wbf,
    const float* __restrict__ ba, float* __restrict__ y) {
  __shared__ __align__(16) unsigned short h2L[16][72];  // 64 o + 8 pad

  const int tid = threadIdx.x;
  const int lane = tid & 63;
  const int wave = tid >> 6;
  const int o0 = blockIdx.x * 64;
  const int n0g = blockIdx.y * 16;

  // ---- phase 1: h2L[n][o_local], wave owns 16 o ----
  {
    floatx4 acc;
    acc[0] = 0.f; acc[1] = 0.f; acc[2] = 0.f; acc[3] = 0.f;
    const int ow = o0 + wave * 16;
#pragma unroll
    for (int kc = 0; kc < 16; ++kc) {
      const int c0 = kc * 32;
      short8 a = (c0 < 256) ? ldfrag(xT, n0g, DD, c0, lane)
                            : ldfrag(msgTb, n0g, DD, c0 - 256, lane);
      short8 b = ldfrag_f32(waf, ow, NN, c0, lane);
      acc = __builtin_amdgcn_mfma_f32_16x16x32_bf16(a, b, acc, 0, 0, 0);
    }
    const int col = lane & 15, q = lane >> 4;
    const float cb = ba[o0 + wave * 16 + col];
#pragma unroll
    for (int r = 0; r < 4; ++r)
      h2L[q * 4 + r][wave * 16 + col] = f2bf(fmaxf(acc[r] + cb, 0.f));
  }
  __syncthreads();

  // ---- phase 2: y[o2][n] += wb[o2][o0:o0+64] @ h2L^T ----
  {
    const int brow = lane & 15;
    const int koff = (lane >> 4) << 3;
    const int col = lane & 15, q = lane >> 4;
#pragma unroll
    for (int t = 0; t < 4; ++t) {
      const int o2t = wave * 64 + t * 16;
      floatx4 acc;
      acc[0] = 0.f; acc[1] = 0.f; acc[2] = 0.f; acc[3] = 0.f;
#pragma unroll
      for (int kc = 0; kc < 2; ++kc) {
        short8 a = ldfrag_f32(wbf, o2t, NN, o0 + kc * 32, lane);
        short8 b = *(const short8*)&h2L[brow][kc * 32 + koff];
        acc = __builtin_amdgcn_mfma_f32_16x16x32_bf16(a, b, acc, 0, 0, 0);
      }
#pragma unroll
      for (int r = 0; r < 4; ++r)
        atomicAdd(&y[(o2t + q * 4 + r) * NN + n0g + col], acc[r]);
    }
  }
}

// ---------------------------------------------------------------------------
extern "C" void kernel_launch(void* const* d_in, const int* in_sizes, int n_in,
                              void* d_out, int out_size, void* d_ws, size_t ws_size,
                              hipStream_t stream) {
  (void)in_sizes; (void)n_in; (void)out_size; (void)ws_size;

  const float* x   = (const float*)d_in[0];
  const float* src = (const float*)d_in[1];
  const float* w1  = (const float*)d_in[2];
  const float* b1  = (const float*)d_in[3];
  const float* w2  = (const float*)d_in[4];
  const float* b2  = (const float*)d_in[5];
  const float* wa  = (const float*)d_in[6];
  const float* ba  = (const float*)d_in[7];
  const float* wb  = (const float*)d_in[8];
  const float* bb  = (const float*)d_in[9];

  float* y_out  = (float*)d_out;            // (256,512)
  float* sc_out = (float*)d_out + 131072;   // (512,512)

  char* ws = (char*)d_ws;
  float*          aq    = (float*)(ws);                          // 512KB
  float*          ak    = (float*)(ws + (512 << 10));            // 512KB
  unsigned short* msgTb = (unsigned short*)(ws + (1024 << 10));  // 256KB
  unsigned short* xT    = (unsigned short*)(ws + (1280 << 10));  // 256KB

  aqak_kernel<<<dim3(16, 16, 3), 256, 0, stream>>>(x, src, w1, b1, bb, aq, ak,
                                                   y_out, xT);
  scores_kernel<<<dim3(16, 16), 512, 0, stream>>>(aq, ak, w2, b2, sc_out);
  msgT_kernel<<<dim3(8, 32), 256, 0, stream>>>(sc_out, src, msgTb);
  h2y_kernel<<<dim3(8, 32), 256, 0, stream>>>(xT, msgTb, wa, wb, ba, y_out);
}

// Round 3
// 100.506 us; speedup vs baseline: 2.0431x; 1.0121x over previous
//
#include <hip/hip_runtime.h>
#include <hip/hip_bf16.h>

#define DD 256
#define NN 512

typedef __attribute__((ext_vector_type(8))) short short8;
typedef __attribute__((ext_vector_type(4))) float floatx4;

// ---- f32 -> bf16 round-to-nearest-even ----
__device__ __forceinline__ unsigned short f2bf(float f) {
  unsigned u = __float_as_uint(f);
  u += 0x7FFFu + ((u >> 16) & 1u);
  return (unsigned short)(u >> 16);
}
__device__ __forceinline__ unsigned pack2(float a, float b) {
  return (unsigned)f2bf(a) | ((unsigned)f2bf(b) << 16);
}

// ---- MFMA fragment from global bf16 rows (k contiguous): one 16B load ----
__device__ __forceinline__ short8 ldfrag(const unsigned short* __restrict__ base,
                                         int row, int ld, int k, int lane) {
  return *(const short8*)(base + (row + (lane & 15)) * ld + k + ((lane >> 4) << 3));
}

// ---- MFMA fragment from global f32 rows (k contiguous): 2 float4 + pack ----
__device__ __forceinline__ short8 ldfrag_f32(const float* __restrict__ base,
                                             int row, int ld, int k, int lane) {
  const float* p = base + (row + (lane & 15)) * ld + k + ((lane >> 4) << 3);
  const float4 v0 = *(const float4*)p;
  const float4 v1 = *(const float4*)(p + 4);
  short8 r;
  r[0] = (short)f2bf(v0.x); r[1] = (short)f2bf(v0.y);
  r[2] = (short)f2bf(v0.z); r[3] = (short)f2bf(v0.w);
  r[4] = (short)f2bf(v1.x); r[5] = (short)f2bf(v1.y);
  r[6] = (short)f2bf(v1.z); r[7] = (short)f2bf(v1.w);
  return r;
}

template <int NF>
__device__ __forceinline__ void acc_zero(floatx4 acc[NF]) {
#pragma unroll
  for (int i = 0; i < NF; ++i) {
    acc[i][0] = 0.f; acc[i][1] = 0.f; acc[i][2] = 0.f; acc[i][3] = 0.f;
  }
}

// Split-K combine across 4 waves via LDS; wave 0 ends with the full sum.
template <int NF>
__device__ __forceinline__ void ksplit_combine(floatx4 acc[NF], float* red,
                                               int wave, int lane) {
  const int W = 16 * NF;
  const int col = lane & 15;
  const int q = lane >> 4;
  if (wave > 0) {
    float* base = red + (wave - 1) * 16 * W;
#pragma unroll
    for (int nf = 0; nf < NF; ++nf)
#pragma unroll
      for (int r = 0; r < 4; ++r)
        base[(q * 4 + r) * W + nf * 16 + col] = acc[nf][r];
  }
  __syncthreads();
  if (wave == 0) {
#pragma unroll
    for (int nf = 0; nf < NF; ++nf)
#pragma unroll
      for (int r = 0; r < 4; ++r) {
        const int idx = (q * 4 + r) * W + nf * 16 + col;
        acc[nf][r] += red[idx] + red[16 * W + idx] + red[32 * W + idx];
      }
  }
}

// Epilogue for C-layout (col = lane&15, row = (lane>>4)*4 + r).
template <int NF, bool COLBIAS, bool ROWBIAS, bool RELU, bool OUTBF>
__device__ __forceinline__ void gemm_epi(floatx4 acc[NF],
    const float* __restrict__ bias, void* __restrict__ C, int ldc,
    int m0, int n0, int lane) {
  const int col = lane & 15;
  const int q = lane >> 4;
#pragma unroll
  for (int nf = 0; nf < NF; ++nf) {
    const int n = n0 + nf * 16 + col;
    const float cb = COLBIAS ? bias[n] : 0.0f;
#pragma unroll
    for (int r = 0; r < 4; ++r) {
      const int m = m0 + q * 4 + r;
      float v = acc[nf][r] + cb + (ROWBIAS ? bias[m] : 0.0f);
      if (RELU) v = fmaxf(v, 0.0f);
      if (OUTBF) ((unsigned short*)C)[m * ldc + n] = f2bf(v);
      else       ((float*)C)[m * ldc + n] = v;
    }
  }
}

// ---------------------------------------------------------------------------
// aqak: aq[d][n] = w1[:, :256] @ x + b1 ; ak[d][n] = w1[:, 256:] @ src (f32).
// grid (16, 16, 3); z==2 blocks additionally hoist ALL downstream bf16
// conversions (xT, src, wa, wb) so msgT/h2y do zero cvt VALU on their
// critical paths. Bit-identical: same f2bf on the same values.
// ---------------------------------------------------------------------------
__global__ __launch_bounds__(256) void aqak_kernel(
    const float* __restrict__ x, const float* __restrict__ src,
    const float* __restrict__ w1, const float* __restrict__ b1,
    const float* __restrict__ bb,
    const float* __restrict__ wa, const float* __restrict__ wb,
    float* __restrict__ aq, float* __restrict__ ak, float* __restrict__ y,
    unsigned short* __restrict__ xT, unsigned short* __restrict__ srcb,
    unsigned short* __restrict__ wab, unsigned short* __restrict__ wbb) {
  __shared__ float red[1536];
  __shared__ __align__(16) float bt[256][33];   // [d][n], +1 pad breaks conflicts

  const int tid = threadIdx.x;
  const int z = blockIdx.z;

  if (z == 2) {
    const int c = blockIdx.y * 16 + blockIdx.x;   // 0..255
    // y init: row o = c
    const float bv = bb[c];
    float2 v; v.x = bv; v.y = bv;
    *(float2*)&y[c * NN + tid * 2] = v;
    // xT cvt: tokens c*2, c*2+1 (256 d each)
    const int n0t = c * 2 + (tid >> 7);
    const int d2 = (tid & 127) * 2;
    const float f0 = x[d2 * NN + n0t];
    const float f1 = x[(d2 + 1) * NN + n0t];
    *(unsigned*)&xT[n0t * DD + d2] = pack2(f0, f1);
    // wa cvt (512x512): one float4 per thread
    {
      const int i4 = c * 256 + tid;               // float4 index, 65536 total
      const float4 w4 = *(const float4*)&wa[i4 * 4];
      unsigned lo = pack2(w4.x, w4.y), hi = pack2(w4.z, w4.w);
      uint2 o; o.x = lo; o.y = hi;
      *(uint2*)&wab[i4 * 4] = o;
    }
    // wb cvt (256x512): one float2 per thread
    {
      const int i2 = c * 256 + tid;               // float2 index, 65536 total
      const float2 w2v = *(const float2*)&wb[i2 * 2];
      *(unsigned*)&wbb[i2 * 2] = pack2(w2v.x, w2v.y);
    }
    // src cvt (256x512, row-major as-is): one float2 per thread
    {
      const int i2 = c * 256 + tid;
      const float2 s2 = *(const float2*)&src[i2 * 2];
      *(unsigned*)&srcb[i2 * 2] = pack2(s2.x, s2.y);
    }
    return;
  }

  const int lane = tid & 63;
  const int wave = tid >> 6;
  const int m0 = blockIdx.y * 16;   // d
  const int n0 = blockIdx.x * 32;   // token
  const float* in = z ? src : x;

  // ---- stage [256 d][32 n] f32 tile, coalesced 128B groups ----
#pragma unroll
  for (int i = 0; i < 8; ++i) {
    const int idx = i * 256 + tid;
    const int row = idx >> 3;
    const int c4 = (idx & 7) * 4;
    *(float4*)&bt[row][c4] = *(const float4*)&in[row * NN + n0 + c4];
  }
  __syncthreads();

  floatx4 acc[2]; acc_zero<2>(acc);
#pragma unroll
  for (int kc = 0; kc < 2; ++kc) {
    const int kl = wave * 64 + kc * 32;
    short8 a = ldfrag_f32(w1, m0, NN, z * 256 + kl, lane);
#pragma unroll
    for (int nf = 0; nf < 2; ++nf) {
      const int n = nf * 16 + (lane & 15);
      const int kk = kl + ((lane >> 4) << 3);
      short8 b;
#pragma unroll
      for (int j = 0; j < 8; ++j) b[j] = (short)f2bf(bt[kk + j][n]);
      acc[nf] = __builtin_amdgcn_mfma_f32_16x16x32_bf16(a, b, acc[nf], 0, 0, 0);
    }
  }
  ksplit_combine<2>(acc, red, wave, lane);
  if (wave == 0) {
    if (z == 0) gemm_epi<2, false, true, false, false>(acc, b1, aq, NN, m0, n0, lane);
    else        gemm_epi<2, false, false, false, false>(acc, nullptr, ak, NN, m0, n0, lane);
  }
}

// ---------------------------------------------------------------------------
// scores: sc[n][m] = b2 + sum_d w2[d] relu(aq[d][n] + ak[d][m])
// grid (16,16) x 512 threads. d split across 8 waves (2 waves/SIMD for
// stall interleave); lane does 4n x 4m outer-product from f32 LDS.
// ---------------------------------------------------------------------------
__global__ __launch_bounds__(512) void scores_kernel(
    const float* __restrict__ aq, const float* __restrict__ ak,
    const float* __restrict__ w2, const float* __restrict__ b2,
    float* __restrict__ sc) {
  __shared__ __align__(16) float aqs[256][36];   // [d][n], 144B rows
  __shared__ __align__(16) float aks[256][36];
  __shared__ __align__(16) float part[8][32][32];
  __shared__ float w2s[DD];

  const int tid = threadIdx.x;
  const int lane = tid & 63;
  const int wave = tid >> 6;
  const int n0 = blockIdx.x * 32;
  const int m0 = blockIdx.y * 32;

  if (tid < DD) w2s[tid] = w2[tid];

  // ---- stage aq/ak tiles (f32, coalesced 128B groups) ----
#pragma unroll
  for (int i = 0; i < 4; ++i) {
    const int idx = i * 512 + tid;
    const int row = idx >> 3;
    const int c4 = (idx & 7) * 4;
    *(float4*)&aqs[row][c4] = *(const float4*)&aq[row * NN + n0 + c4];
    *(float4*)&aks[row][c4] = *(const float4*)&ak[row * NN + m0 + c4];
  }
  __syncthreads();

  // ---- outer-product phase: wave covers 32 d; lane = (nq 0..7, mq 0..7) ----
  {
    const int nq = lane & 7;
    const int mq = lane >> 3;
    float s[4][4];
#pragma unroll
    for (int i = 0; i < 4; ++i)
#pragma unroll
      for (int j = 0; j < 4; ++j) s[i][j] = 0.f;

    const int dbeg = wave * 32;
    for (int dd = dbeg; dd < dbeg + 32; ++dd) {
      const float4 a4 = *(const float4*)&aqs[dd][nq * 4];
      const float4 k4 = *(const float4*)&aks[dd][mq * 4];
      const float w = w2s[dd];
      const float a[4] = {a4.x, a4.y, a4.z, a4.w};
      const float k[4] = {k4.x, k4.y, k4.z, k4.w};
#pragma unroll
      for (int i = 0; i < 4; ++i)
#pragma unroll
        for (int j = 0; j < 4; ++j)
          s[i][j] += w * fmaxf(a[i] + k[j], 0.f);
    }
#pragma unroll
    for (int i = 0; i < 4; ++i) {
      float4 o; o.x = s[i][0]; o.y = s[i][1]; o.z = s[i][2]; o.w = s[i][3];
      *(float4*)&part[wave][nq * 4 + i][mq * 4] = o;
    }
  }
  __syncthreads();

  // ---- combine 8 wave-partials + b2, write sc ----
  if (tid < 256) {
    const int n = tid >> 3;
    const int mg = (tid & 7) * 4;
    const float bv = b2[0];
    float4 o; o.x = bv; o.y = bv; o.z = bv; o.w = bv;
#pragma unroll
    for (int wv = 0; wv < 8; ++wv) {
      const float4 p = *(const float4*)&part[wv][n][mg];
      o.x += p.x; o.y += p.y; o.z += p.z; o.w += p.w;
    }
    *(float4*)&sc[(n0 + n) * NN + m0 + mg] = o;
  }
}

// ---------------------------------------------------------------------------
// msgT: softmax(sc rows) fused with P @ src^T (bf16 out); src read as
// PRECONVERTED bf16 (srcb) — zero cvt VALU in the PV loop.
// grid (8 d-tiles of 32, 32 n-tiles) = 256 blocks; split-K/4 over m.
// ---------------------------------------------------------------------------
__global__ __launch_bounds__(256) void msgT_kernel(
    const float* __restrict__ sc, const unsigned short* __restrict__ srcb,
    unsigned short* __restrict__ msgTb) {
  __shared__ unsigned short Ap[16][520];
  __shared__ float red[1536];
  __shared__ float smax[16][16];
  __shared__ float ssum[16][16];
  __shared__ float rst[16][2];

  const int tid = threadIdx.x;
  const int lane = tid & 63;
  const int wave = tid >> 6;
  const int n0 = blockIdx.y * 16;
  const int d0 = blockIdx.x * 32;

  const int r = tid >> 4;
  const int c = tid & 15;
  float4 v[8];
  const float* rp = sc + (n0 + r) * NN + c * 4;
#pragma unroll
  for (int i = 0; i < 8; ++i) v[i] = *(const float4*)(rp + i * 64);

  float mx = -3.0e38f;
#pragma unroll
  for (int i = 0; i < 8; ++i)
    mx = fmaxf(mx, fmaxf(fmaxf(v[i].x, v[i].y), fmaxf(v[i].z, v[i].w)));
  smax[r][c] = mx;
  __syncthreads();
  if (c == 0) {
    float m2 = smax[r][0];
#pragma unroll
    for (int i = 1; i < 16; ++i) m2 = fmaxf(m2, smax[r][i]);
    rst[r][0] = m2;
  }
  __syncthreads();
  mx = rst[r][0];

  float sum = 0.f;
#pragma unroll
  for (int i = 0; i < 8; ++i) {
    v[i].x = __expf(v[i].x - mx); v[i].y = __expf(v[i].y - mx);
    v[i].z = __expf(v[i].z - mx); v[i].w = __expf(v[i].w - mx);
    sum += v[i].x + v[i].y + v[i].z + v[i].w;
  }
  ssum[r][c] = sum;
  __syncthreads();
  if (c == 0) {
    float s2 = ssum[r][0];
#pragma unroll
    for (int i = 1; i < 16; ++i) s2 += ssum[r][i];
    rst[r][1] = s2;
  }
  __syncthreads();
  const float inv = 1.0f / rst[r][1];
#pragma unroll
  for (int i = 0; i < 8; ++i) {
    *(unsigned*)&Ap[r][c * 4 + i * 64]     = pack2(v[i].x * inv, v[i].y * inv);
    *(unsigned*)&Ap[r][c * 4 + i * 64 + 2] = pack2(v[i].z * inv, v[i].w * inv);
  }
  __syncthreads();

  floatx4 acc[2]; acc_zero<2>(acc);
  const int k0w = wave * 128;
  const int arow = lane & 15;
  const int koff = (lane >> 4) << 3;
#pragma unroll
  for (int k = 0; k < 128; k += 32) {
    short8 a = *(const short8*)&Ap[arow][k0w + k + koff];
#pragma unroll
    for (int nf = 0; nf < 2; ++nf) {
      short8 b = ldfrag(srcb, d0 + nf * 16, NN, k0w + k, lane);
      acc[nf] = __builtin_amdgcn_mfma_f32_16x16x32_bf16(a, b, acc[nf], 0, 0, 0);
    }
  }
  ksplit_combine<2>(acc, red, wave, lane);
  if (wave == 0)
    gemm_epi<2, false, false, false, true>(acc, nullptr, msgTb, DD, n0, d0, lane);
}

// ---------------------------------------------------------------------------
// h2y: h2 o-slice = relu([x|msg] @ wa^T + ba) in LDS (bf16), then
//      y[o2][n] += wb[o2][o-slice] @ h2^T via f32 atomicAdd (y pre-set to bb).
// wa/wb read as PRECONVERTED bf16 (wab/wbb) — removes ~400 cvt-VALU cycles
// per lane from the critical path. grid (8 o-slices of 64, 32 n-tiles of 16).
// ---------------------------------------------------------------------------
__global__ __launch_bounds__(256) void h2y_kernel(
    const unsigned short* __restrict__ xT, const unsigned short* __restrict__ msgTb,
    const unsigned short* __restrict__ wab, const unsigned short* __restrict__ wbb,
    const float* __restrict__ ba, float* __restrict__ y) {
  __shared__ __align__(16) unsigned short h2L[16][72];  // 64 o + 8 pad

  const int tid = threadIdx.x;
  const int lane = tid & 63;
  const int wave = tid >> 6;
  const int o0 = blockIdx.x * 64;
  const int n0g = blockIdx.y * 16;

  // ---- phase 1: h2L[n][o_local], wave owns 16 o ----
  {
    floatx4 acc;
    acc[0] = 0.f; acc[1] = 0.f; acc[2] = 0.f; acc[3] = 0.f;
    const int ow = o0 + wave * 16;
#pragma unroll
    for (int kc = 0; kc < 16; ++kc) {
      const int c0 = kc * 32;
      short8 a = (c0 < 256) ? ldfrag(xT, n0g, DD, c0, lane)
                            : ldfrag(msgTb, n0g, DD, c0 - 256, lane);
      short8 b = ldfrag(wab, ow, NN, c0, lane);
      acc = __builtin_amdgcn_mfma_f32_16x16x32_bf16(a, b, acc, 0, 0, 0);
    }
    const int col = lane & 15, q = lane >> 4;
    const float cb = ba[o0 + wave * 16 + col];
#pragma unroll
    for (int r = 0; r < 4; ++r)
      h2L[q * 4 + r][wave * 16 + col] = f2bf(fmaxf(acc[r] + cb, 0.f));
  }
  __syncthreads();

  // ---- phase 2: y[o2][n] += wb[o2][o0:o0+64] @ h2L^T ----
  {
    const int brow = lane & 15;
    const int koff = (lane >> 4) << 3;
    const int col = lane & 15, q = lane >> 4;
#pragma unroll
    for (int t = 0; t < 4; ++t) {
      const int o2t = wave * 64 + t * 16;
      floatx4 acc;
      acc[0] = 0.f; acc[1] = 0.f; acc[2] = 0.f; acc[3] = 0.f;
#pragma unroll
      for (int kc = 0; kc < 2; ++kc) {
        short8 a = ldfrag(wbb, o2t, NN, o0 + kc * 32, lane);
        short8 b = *(const short8*)&h2L[brow][kc * 32 + koff];
        acc = __builtin_amdgcn_mfma_f32_16x16x32_bf16(a, b, acc, 0, 0, 0);
      }
#pragma unroll
      for (int r = 0; r < 4; ++r)
        atomicAdd(&y[(o2t + q * 4 + r) * NN + n0g + col], acc[r]);
    }
  }
}

// ---------------------------------------------------------------------------
extern "C" void kernel_launch(void* const* d_in, const int* in_sizes, int n_in,
                              void* d_out, int out_size, void* d_ws, size_t ws_size,
                              hipStream_t stream) {
  (void)in_sizes; (void)n_in; (void)out_size; (void)ws_size;

  const float* x   = (const float*)d_in[0];
  const float* src = (const float*)d_in[1];
  const float* w1  = (const float*)d_in[2];
  const float* b1  = (const float*)d_in[3];
  const float* w2  = (const float*)d_in[4];
  const float* b2  = (const float*)d_in[5];
  const float* wa  = (const float*)d_in[6];
  const float* ba  = (const float*)d_in[7];
  const float* wb  = (const float*)d_in[8];
  const float* bb  = (const float*)d_in[9];

  float* y_out  = (float*)d_out;            // (256,512)
  float* sc_out = (float*)d_out + 131072;   // (512,512)

  char* ws = (char*)d_ws;
  float*          aq    = (float*)(ws);                          // 512KB
  float*          ak    = (float*)(ws + (512 << 10));            // 512KB
  unsigned short* msgTb = (unsigned short*)(ws + (1024 << 10));  // 256KB
  unsigned short* xT    = (unsigned short*)(ws + (1280 << 10));  // 256KB
  unsigned short* srcb  = (unsigned short*)(ws + (1536 << 10));  // 256KB
  unsigned short* wab   = (unsigned short*)(ws + (1792 << 10));  // 512KB
  unsigned short* wbb   = (unsigned short*)(ws + (2304 << 10));  // 256KB

  aqak_kernel<<<dim3(16, 16, 3), 256, 0, stream>>>(
      x, src, w1, b1, bb, wa, wb, aq, ak, y_out, xT, srcb, wab, wbb);
  scores_kernel<<<dim3(16, 16), 512, 0, stream>>>(aq, ak, w2, b2, sc_out);
  msgT_kernel<<<dim3(8, 32), 256, 0, stream>>>(sc_out, srcb, msgTb);
  h2y_kernel<<<dim3(8, 32), 256, 0, stream>>>(xT, msgTb, wab, wbb, ba, y_out);
}